// Round 20
// baseline (219.822 us; speedup 1.0000x reference)
//
#include <hip/hip_runtime.h>

// Dense dilated KNN graph. B=2, C=64, N=8192, k_total=18, keep ::2 -> 9.
// r20: hh-only candidate GEMM (lo plane deleted; key noise sigma~2e-3 vs
// 4e-3 gaps, margins widened: KM 16->20, M1 14->16; exact-np finalize still
// decides). Per-wave stage halves -> LDS union 50.7KB -> 3 blocks/CU
// (launch_bounds(256,3), 12 waves). Stage VMEM 6/tile (vmcnt(6)), MFMA 8/tile.
// ws: hi 2MB | w16 2MB | sq 64KB | cand u16 [B*N][80] 2.62MB = 6.7MB.

#define NPTS  8192
#define CHN   64
#define NB    2
#define KF    18
#define KC    8
#define KM    20
#define KM1   16
#define KOUT  9
#define NPART 4
#define TPB   32

typedef unsigned u32;
typedef unsigned short u16;
typedef unsigned long long u64;
typedef __attribute__((ext_vector_type(4))) unsigned u32x4;
typedef __attribute__((ext_vector_type(8))) short bf16x8;
typedef __attribute__((ext_vector_type(4))) float f32x4;

__device__ __forceinline__ u32 umin32(u32 a, u32 b) { return a < b ? a : b; }

__device__ __forceinline__ u32 mono32(float f) {
  const u32 u = __float_as_uint(f);
  const u32 s = (u32)((int)u >> 31);
  return u ^ (s | 0x80000000u);
}

__device__ __forceinline__ u32 med3u(u32 a, u32 b, u32 c) {
  u32 r;
  asm("v_med3_u32 %0, %1, %2, %3" : "=v"(r) : "v"(a), "v"(b), "v"(c));
  return r;
}

template <int KK>
__device__ __forceinline__ void insmm(u32 key, u32 (&d)[KK]) {
#pragma unroll
  for (int k = KK - 1; k >= 1; --k) d[k] = med3u(d[k - 1], d[k], key);
  d[0] = umin32(d[0], key);
}

template <int KK>
__device__ __forceinline__ void ins64(u64 key, u64 (&d)[KK]) {
  if (key < d[KK - 1]) {
#pragma unroll
    for (int k = KK - 1; k >= 1; --k) {
      const bool up = d[k - 1] > key;
      const bool here = (!up) && (d[k] > key);
      d[k] = up ? d[k - 1] : (here ? key : d[k]);
    }
    if (d[0] > key) d[0] = key;
  }
}

__device__ __forceinline__ void gload_lds16(const u32* g, u32* l) {
  __builtin_amdgcn_global_load_lds(
      (const __attribute__((address_space(1))) u32*)g,
      (__attribute__((address_space(3))) u32*)l, 16, 0, 0);
}

__device__ __forceinline__ void np_normalize(const float* __restrict__ xb,
                                             float (&v)[CHN]) {
  float ss = 0.f;
#pragma unroll
  for (int c = 0; c < CHN; ++c) {
    v[c] = xb[(size_t)c * NPTS];
    ss = __fadd_rn(ss, __fmul_rn(v[c], v[c]));
  }
  const float den = fmaxf(__fsqrt_rn(ss), 1e-12f);
#pragma unroll
  for (int c = 0; c < CHN; ++c) v[c] = __fdiv_rn(v[c], den);
}

// ---------------- kernel 1: normalize + sq + hi/w16 planes ----------------
__global__ __launch_bounds__(128) void prep_kernel(
    const float* __restrict__ x, u32* __restrict__ hib,
    u32* __restrict__ w16b, float* __restrict__ sq) {
  const int b = blockIdx.x >> 6;
  const int n = ((blockIdx.x & 63) << 7) + threadIdx.x;
  const int g = (b << 13) + n;
  float v[CHN];
  np_normalize(x + (size_t)b * CHN * NPTS + n, v);
  float r[8];
#pragma unroll
  for (int j = 0; j < 8; ++j) r[j] = __fmul_rn(v[j], v[j]);
#pragma unroll
  for (int blk = 1; blk < 8; ++blk)
#pragma unroll
    for (int j = 0; j < 8; ++j)
      r[j] = __fadd_rn(r[j], __fmul_rn(v[8 * blk + j], v[8 * blk + j]));
  const float t0 = __fadd_rn(r[0], r[1]);
  const float t1 = __fadd_rn(r[2], r[3]);
  const float t2 = __fadd_rn(r[4], r[5]);
  const float t3 = __fadd_rn(r[6], r[7]);
  sq[g] = __fadd_rn(__fadd_rn(t0, t1), __fadd_rn(t2, t3));
  u32* hd = hib + (size_t)g * 32;
  u32* wd = w16b + (size_t)g * 32;
  const int key = n & 7;
#pragma unroll
  for (int q = 0; q < 8; ++q) {
    u32 h[4], w[4];
#pragma unroll
    for (int p2 = 0; p2 < 4; ++p2) {
      const u32 ba = __float_as_uint(v[8 * q + 2 * p2]);
      const u32 bc = __float_as_uint(v[8 * q + 2 * p2 + 1]);
      h[p2] = __builtin_amdgcn_perm(bc, ba, 0x07060302u);   // top16(c):top16(a)
      w[p2] = __builtin_amdgcn_perm(bc, ba, 0x05040100u);   // low16(c):low16(a)
    }
    const int pq = (q ^ key) << 2;
    *(u32x4*)(hd + pq) = (u32x4){h[0], h[1], h[2], h[3]};
    *(u32x4*)(wd + pq) = (u32x4){w[0], w[1], w[2], w[3]};
  }
}

// ---------------- kernel 2: hh-only MFMA GEMM + reg-select + merge ----------
__global__ __launch_bounds__(256, 3) void knn_part_kernel(
    const u32* __restrict__ hib, const float* __restrict__ sq,
    u16* __restrict__ cand) {
  // union: main-loop per-wave stage (4 waves x 2 bufs x 1024 u32 = 8192)
  //        merge: dmp[8448] | m1b[4224] @8448 ; m2b aliases dmp.  50.7KB
  __shared__ __align__(16) u32 smem[12672];

  const int tid = threadIdx.x;
  const int vb = ((blockIdx.x & 7) << 7) + (blockIdx.x >> 3);
  const int part = vb >> 8;
  const int w = vb & 255;
  const int b = w >> 7;
  const int qbase = (w & 127) << 6;
  const int t_lo = part << 5;
  const u32* __restrict__ hb_ = hib + ((size_t)b << 18);
  const float* __restrict__ sqb = sq + (b << 13);

  const int lane = tid & 63, wid = tid >> 6;
  const int qoff = (wid & 1) << 5;
  const int moff = (wid >> 1) << 5;
  const int l15 = lane & 15;
  const int h4 = lane >> 4;
  const int sw = l15 & 7;
  const int lofs = lane << 2;
  u32* wstage = smem + (wid << 11);          // 2 bufs x 1024

#define STAGE(BUF, TILE)                                                     \
  {                                                                          \
    const u32* sH_ = hb_ + ((size_t)(TILE) << 11) + (moff << 5);             \
    u32* bp_ = wstage + ((BUF) << 10);                                       \
    gload_lds16(sH_ + lofs, bp_ + lofs);                                     \
    gload_lds16(sH_ + 256 + lofs, bp_ + 256 + lofs);                         \
    gload_lds16(sH_ + 512 + lofs, bp_ + 512 + lofs);                         \
    gload_lds16(sH_ + 768 + lofs, bp_ + 768 + lofs);                         \
  }

  STAGE(0, t_lo)
  float sqn0 = sqb[(t_lo << 6) + moff + l15];
  float sqn1 = sqb[(t_lo << 6) + moff + 16 + l15];

  // A fragments (hi only), negated: A = -Q
  bf16x8 ah[2][2];
#pragma unroll
  for (int g = 0; g < 2; ++g)
#pragma unroll
    for (int s = 0; s < 2; ++s) {
      const int row = qbase + qoff + (g << 4) + l15;
      const int off = row * 32 + ((((s << 2) + h4) ^ sw) << 2);
      u32x4 hv = *(const u32x4*)(hb_ + off);
      hv.x ^= 0x80008000u; hv.y ^= 0x80008000u;
      hv.z ^= 0x80008000u; hv.w ^= 0x80008000u;
      ah[g][s] = __builtin_bit_cast(bf16x8, hv);
    }
  asm volatile("s_waitcnt vmcnt(0)" ::: "memory");
  __builtin_amdgcn_sched_barrier(0);

  u32 d[2][4][KC];
#pragma unroll
  for (int g = 0; g < 2; ++g)
#pragma unroll
    for (int i = 0; i < 4; ++i)
#pragma unroll
      for (int k = 0; k < KC; ++k) d[g][i][k] = 0xffffffffu;

  for (int tau = 0; tau < TPB; ++tau) {
    const int cur = tau & 1;
    const float sq0 = sqn0, sq1 = sqn1;
    if (tau + 1 < TPB) {
      STAGE(cur ^ 1, t_lo + tau + 1)
      sqn0 = sqb[((t_lo + tau + 1) << 6) + moff + l15];
      sqn1 = sqb[((t_lo + tau + 1) << 6) + moff + 16 + l15];
      asm volatile("s_waitcnt vmcnt(6)" ::: "memory");
    } else {
      asm volatile("s_waitcnt vmcnt(0)" ::: "memory");
    }
    __builtin_amdgcn_sched_barrier(0);

    const u32* ppc = wstage + (cur << 10);
#pragma unroll
    for (int f = 0; f < 2; ++f) {
      const float sqm = ((f ? sq1 : sq0) + 2.f) * 0.5f;
      const int rloc = (f << 4) + l15;
      f32x4 acc[2];
      acc[0] = (f32x4){sqm, sqm, sqm, sqm};
      acc[1] = acc[0];
#pragma unroll
      for (int s = 0; s < 2; ++s) {
        const u32* hp = ppc + rloc * 32 + ((((s << 2) + h4) ^ sw) << 2);
        const bf16x8 bh = __builtin_bit_cast(bf16x8, *(const u32x4*)hp);
        acc[0] = __builtin_amdgcn_mfma_f32_16x16x32_bf16(ah[0][s], bh, acc[0], 0, 0, 0);
        acc[1] = __builtin_amdgcn_mfma_f32_16x16x32_bf16(ah[1][s], bh, acc[1], 0, 0, 0);
      }
      const u32 lidx = (u32)((tau << 6) + moff + rloc);
#pragma unroll
      for (int g = 0; g < 2; ++g)
#pragma unroll
        for (int i = 0; i < 4; ++i) {
          const u32 keyv = (__float_as_uint(acc[g][i]) & 0xfffff000u) | lidx;
          insmm<KC>(keyv, d[g][i]);
        }
    }
  }
#undef STAGE
  __syncthreads();

  // ---- transposed bank-skewed merge (two 32-row chunks), M1=16, KM=20 ----
  u32* dmp = smem;              // [k<8][stream*33 + rowc]  8448
  u32* m1b = smem + 8448;       // [j<16][oct*33 + rowc]    4224
  u32* m2b = smem;              // [k<20][half*33 + rowc]   1320 (aliases dmp)
  const int stream = ((wid >> 1) << 4) + l15;
  const int rcb = ((wid & 1) << 4) + (h4 << 2);
#pragma unroll
  for (int chunk = 0; chunk < 2; ++chunk) {
#pragma unroll
    for (int i = 0; i < 4; ++i) {
      const int col = stream * 33 + rcb + i;
#pragma unroll
      for (int k = 0; k < KC; ++k) dmp[k * 1056 + col] = d[chunk][i][k];
    }
    __syncthreads();
    // M1: 256 thr (rowc, oct): 4 streams x 8 -> top-16
    {
      const int rowc = tid >> 3, oct = tid & 7;
      u32 m1[KM1];
#pragma unroll
      for (int k = 0; k < KM1; ++k) m1[k] = 0xffffffffu;
#pragma unroll
      for (int s = 0; s < 4; ++s) {
        const int col = (oct * 4 + s) * 33 + rowc;
#pragma unroll
        for (int j = 0; j < KC; ++j) insmm<KM1>(dmp[j * 1056 + col], m1);
      }
      const int col = oct * 33 + rowc;
#pragma unroll
      for (int k = 0; k < KM1; ++k) m1b[k * 264 + col] = m1[k];
    }
    __syncthreads();
    // M2: 64 thr (rowc, half): 4 octs x 16 -> top-20 (writes alias dmp)
    if (tid < 64) {
      const int rowc = tid >> 1, half = tid & 1;
      u32 m2[KM];
#pragma unroll
      for (int k = 0; k < KM; ++k) m2[k] = 0xffffffffu;
#pragma unroll
      for (int o = 0; o < 4; ++o) {
        const int col = (half * 4 + o) * 33 + rowc;
#pragma unroll
        for (int j = 0; j < KM1; ++j) insmm<KM>(m1b[j * 264 + col], m2);
      }
      const int col = half * 33 + rowc;
#pragma unroll
      for (int k = 0; k < KM; ++k) m2b[k * 66 + col] = m2[k];
    }
    __syncthreads();
    // M3: 32 thr (rowc): 2 halves x 20 -> top-20 -> cand
    if (tid < 32) {
      u32 m3[KM];
#pragma unroll
      for (int k = 0; k < KM; ++k) m3[k] = 0xffffffffu;
#pragma unroll
      for (int h = 0; h < 2; ++h) {
        const int col = h * 33 + tid;
#pragma unroll
        for (int k = 0; k < KM; ++k) insmm<KM>(m2b[k * 66 + col], m3);
      }
      const int row = ((tid >> 4) << 5) + (chunk << 4) + (tid & 15);
      const int rg = (b << 13) + qbase + row;
      u16* cw = cand + (size_t)rg * (NPART * KM) + part * KM;
#pragma unroll
      for (int k = 0; k < KM; ++k)
        cw[k] = (u16)((part << 11) + (m3[k] & 0xfffu));
    }
    __syncthreads();
  }
}

// ---------------- kernel 3: rescore from hi|w16 exact reconstruct -----------
__global__ __launch_bounds__(512) void finalize_kernel(
    const u32* __restrict__ hib, const u32* __restrict__ w16b,
    const float* __restrict__ sq, const u16* __restrict__ cand,
    int* __restrict__ out) {
  __shared__ u64 ex[64 * 81];
  __shared__ u64 hf[128 * 19];
  const int tid = threadIdx.x;
  const int rl = tid >> 3, sub = tid & 7;
  const int row = (blockIdx.x << 6) + rl;
  const int b = row >> 13;
  const int n = row & 8191;
  const float sqn = sq[row];
  const float* __restrict__ sqb = sq + (b << 13);
  const u32* __restrict__ hb_ = hib + ((size_t)b << 18);
  const u32* __restrict__ wb_ = w16b + ((size_t)b << 18);
  float vq[CHN];
  {
    const u32* hq = hb_ + ((size_t)n << 5);
    const u32* wq = wb_ + ((size_t)n << 5);
    const int key = n & 7;
#pragma unroll
    for (int q = 0; q < 8; ++q) {
      const int pq = (q ^ key) << 2;
      const u32x4 hw = *(const u32x4*)(hq + pq);
      const u32x4 ww = *(const u32x4*)(wq + pq);
      const u32 hv[4] = {hw.x, hw.y, hw.z, hw.w};
      const u32 wv[4] = {ww.x, ww.y, ww.z, ww.w};
#pragma unroll
      for (int p2 = 0; p2 < 4; ++p2) {
        vq[8 * q + 2 * p2] =
            __uint_as_float((hv[p2] << 16) | (wv[p2] & 0xffffu));
        vq[8 * q + 2 * p2 + 1] =
            __uint_as_float((hv[p2] & 0xffff0000u) | (wv[p2] >> 16));
      }
    }
  }
  const u16* __restrict__ cr = cand + (size_t)row * 80 + sub * 10;
  u64* exw = ex + rl * 81 + sub * 10;
  for (int j = 0; j < 10; ++j) {
    const int ix = cr[j];
    const u32* hp = hb_ + ((size_t)ix << 5);
    const u32* wp = wb_ + ((size_t)ix << 5);
    const int key = ix & 7;
    float dot = 0.f;
#pragma unroll
    for (int q = 0; q < 8; ++q) {
      const int pq = (q ^ key) << 2;
      const u32x4 hw = *(const u32x4*)(hp + pq);
      const u32x4 ww = *(const u32x4*)(wp + pq);
      const u32 hv[4] = {hw.x, hw.y, hw.z, hw.w};
      const u32 wv[4] = {ww.x, ww.y, ww.z, ww.w};
#pragma unroll
      for (int p2 = 0; p2 < 4; ++p2) {
        const float a = __uint_as_float((hv[p2] << 16) | (wv[p2] & 0xffffu));
        const float c = __uint_as_float((hv[p2] & 0xffff0000u) | (wv[p2] >> 16));
        dot = __fadd_rn(dot, __fmul_rn(vq[8 * q + 2 * p2], a));
        dot = __fadd_rn(dot, __fmul_rn(vq[8 * q + 2 * p2 + 1], c));
      }
    }
    const float dist =
        __fadd_rn(__fsub_rn(sqn, __fmul_rn(2.0f, dot)), sqb[ix]);
    exw[j] = ((u64)mono32(dist) << 32) | (u32)ix;
  }
  __syncthreads();
  if (tid < 128) {
    const int r2 = tid >> 1, hv = tid & 1;
    u64 m18[KF];
#pragma unroll
    for (int k = 0; k < KF; ++k) m18[k] = ~0ull;
    const u64* p = ex + r2 * 81 + hv * 40;
    for (int j = 0; j < 40; ++j) ins64<KF>(p[j], m18);
    u64* wr = hf + tid * 19;
#pragma unroll
    for (int k = 0; k < KF; ++k) wr[k] = m18[k];
  }
  __syncthreads();
  if (tid < 64) {
    u64 m18[KF];
#pragma unroll
    for (int k = 0; k < KF; ++k) m18[k] = ~0ull;
    const u64* p0 = hf + (tid << 1) * 19;
    const u64* p1 = hf + ((tid << 1) + 1) * 19;
    for (int j = 0; j < KF; ++j) ins64<KF>(p0[j], m18);
    for (int j = 0; j < KF; ++j) ins64<KF>(p1[j], m18);
    const int row2 = (blockIdx.x << 6) + tid;
    int* o0 = out + (size_t)row2 * KOUT;
    int* o1 = o0 + NB * NPTS * KOUT;
#pragma unroll
    for (int k = 0; k < KOUT; ++k) {
      o0[k] = (int)(m18[2 * k] & 0xffffffffu);
      o1[k] = row2 & 8191;
    }
  }
}

// ---------------- launcher: 3 kernels, ws = 6.7MB ----------------
extern "C" void kernel_launch(void* const* d_in, const int* in_sizes, int n_in,
                              void* d_out, int out_size, void* d_ws, size_t ws_size,
                              hipStream_t stream) {
  const float* x = (const float*)d_in[0];
  u32* hib = (u32*)d_ws;                                 // 2MB @0
  u32* w16b = hib + (size_t)NB * NPTS * 32;              // 2MB @2MB
  float* sqg = (float*)(w16b + (size_t)NB * NPTS * 32);  // 64KB @4MB
  u16* cand = (u16*)(sqg + NB * NPTS);                   // 2.62MB
  int* out = (int*)d_out;
  prep_kernel<<<dim3(128), dim3(128), 0, stream>>>(x, hib, w16b, sqg);
  knn_part_kernel<<<dim3(1024), dim3(256), 0, stream>>>(hib, sqg, cand);
  finalize_kernel<<<dim3(256), dim3(512), 0, stream>>>(hib, w16b, sqg, cand, out);
}

// Round 21
// 201.956 us; speedup vs baseline: 1.0885x; 1.0885x over previous
//
#include <hip/hip_runtime.h>

// Dense dilated KNN graph. B=2, C=64, N=8192, k_total=18, keep ::2 -> 9.
// FINAL (= r19, measured 202.1us total / 134.5us knn_part, absmax 0):
//  prep: np-exact normalize + sq + split-bf16 hi plane + w16 low-bits plane
//        (XOR-quad pre-swizzle for conflict-free MFMA fragment reads).
//  knn_part: barrier-free main loop — per-wave private double-buffered LDS
//        stage via global_load_lds(16B), counted s_waitcnt vmcnt(10);
//        split-bf16 MFMA (hh+hl+lh) computes keys directly in accumulators
//        (C-init (sq_m+2)/2, A=-Q -> positive float = raw-bit-monotone key);
//        branchless med3-based per-lane top-8 lists; transposed bank-skewed
//        3-level in-block merge (stride 33/264/66) -> top-16 per part.
//  finalize: bit-exact numpy-fp32 rescore of 64 candidates/row from
//        hi|w16-reconstructed f32, lexicographic (dist, idx) top-18, ::2.
// ws: hi 2MB | lo 2MB | w16 2MB | sq 64KB | cand u16 [B*N][64] 2MB = 8.06MB.

#define NPTS  8192
#define CHN   64
#define NB    2
#define KF    18
#define KC    8
#define KM    16
#define KOUT  9
#define NPART 4
#define TPB   32

typedef unsigned u32;
typedef unsigned short u16;
typedef unsigned long long u64;
typedef __attribute__((ext_vector_type(4))) unsigned u32x4;
typedef __attribute__((ext_vector_type(8))) short bf16x8;
typedef __attribute__((ext_vector_type(4))) float f32x4;

__device__ __forceinline__ u32 umin32(u32 a, u32 b) { return a < b ? a : b; }

__device__ __forceinline__ u32 mono32(float f) {
  const u32 u = __float_as_uint(f);
  const u32 s = (u32)((int)u >> 31);
  return u ^ (s | 0x80000000u);
}

__device__ __forceinline__ u32 med3u(u32 a, u32 b, u32 c) {
  u32 r;
  asm("v_med3_u32 %0, %1, %2, %3" : "=v"(r) : "v"(a), "v"(b), "v"(c));
  return r;
}

template <int KK>
__device__ __forceinline__ void insmm(u32 key, u32 (&d)[KK]) {
#pragma unroll
  for (int k = KK - 1; k >= 1; --k) d[k] = med3u(d[k - 1], d[k], key);
  d[0] = umin32(d[0], key);
}

template <int KK>
__device__ __forceinline__ void ins64(u64 key, u64 (&d)[KK]) {
  if (key < d[KK - 1]) {
#pragma unroll
    for (int k = KK - 1; k >= 1; --k) {
      const bool up = d[k - 1] > key;
      const bool here = (!up) && (d[k] > key);
      d[k] = up ? d[k - 1] : (here ? key : d[k]);
    }
    if (d[0] > key) d[0] = key;
  }
}

__device__ __forceinline__ void gload_lds16(const u32* g, u32* l) {
  __builtin_amdgcn_global_load_lds(
      (const __attribute__((address_space(1))) u32*)g,
      (__attribute__((address_space(3))) u32*)l, 16, 0, 0);
}

__device__ __forceinline__ void np_normalize(const float* __restrict__ xb,
                                             float (&v)[CHN]) {
  float ss = 0.f;
#pragma unroll
  for (int c = 0; c < CHN; ++c) {
    v[c] = xb[(size_t)c * NPTS];
    ss = __fadd_rn(ss, __fmul_rn(v[c], v[c]));
  }
  const float den = fmaxf(__fsqrt_rn(ss), 1e-12f);
#pragma unroll
  for (int c = 0; c < CHN; ++c) v[c] = __fdiv_rn(v[c], den);
}

// ---------------- kernel 1: normalize + sq + presplit hi/lo + w16 -----------
__global__ __launch_bounds__(128) void prep_kernel(
    const float* __restrict__ x, u32* __restrict__ hib, u32* __restrict__ lob,
    u32* __restrict__ w16b, float* __restrict__ sq) {
  const int b = blockIdx.x >> 6;
  const int n = ((blockIdx.x & 63) << 7) + threadIdx.x;
  const int g = (b << 13) + n;
  float v[CHN];
  np_normalize(x + (size_t)b * CHN * NPTS + n, v);
  float r[8];
#pragma unroll
  for (int j = 0; j < 8; ++j) r[j] = __fmul_rn(v[j], v[j]);
#pragma unroll
  for (int blk = 1; blk < 8; ++blk)
#pragma unroll
    for (int j = 0; j < 8; ++j)
      r[j] = __fadd_rn(r[j], __fmul_rn(v[8 * blk + j], v[8 * blk + j]));
  const float t0 = __fadd_rn(r[0], r[1]);
  const float t1 = __fadd_rn(r[2], r[3]);
  const float t2 = __fadd_rn(r[4], r[5]);
  const float t3 = __fadd_rn(r[6], r[7]);
  sq[g] = __fadd_rn(__fadd_rn(t0, t1), __fadd_rn(t2, t3));
  u32* hd = hib + (size_t)g * 32;
  u32* ld = lob + (size_t)g * 32;
  u32* wd = w16b + (size_t)g * 32;
  const int key = n & 7;
#pragma unroll
  for (int q = 0; q < 8; ++q) {
    u32 h[4], l[4], w[4];
#pragma unroll
    for (int p2 = 0; p2 < 4; ++p2) {
      const float a = v[8 * q + 2 * p2];
      const float c = v[8 * q + 2 * p2 + 1];
      const u32 ba = __float_as_uint(a), bc = __float_as_uint(c);
      const float la = a - __uint_as_float(ba & 0xffff0000u);
      const float lc = c - __uint_as_float(bc & 0xffff0000u);
      h[p2] = __builtin_amdgcn_perm(bc, ba, 0x07060302u);
      l[p2] = __builtin_amdgcn_perm(__float_as_uint(lc), __float_as_uint(la),
                                    0x07060302u);
      w[p2] = __builtin_amdgcn_perm(bc, ba, 0x05040100u);
    }
    const int pq = (q ^ key) << 2;
    *(u32x4*)(hd + pq) = (u32x4){h[0], h[1], h[2], h[3]};
    *(u32x4*)(ld + pq) = (u32x4){l[0], l[1], l[2], l[3]};
    *(u32x4*)(wd + pq) = (u32x4){w[0], w[1], w[2], w[3]};
  }
}

// ---------------- kernel 2: barrier-free MFMA GEMM + skewed merge -----------
__global__ __launch_bounds__(256, 2) void knn_part_kernel(
    const u32* __restrict__ hib, const u32* __restrict__ lob,
    const float* __restrict__ sq, u16* __restrict__ cand) {
  __shared__ __align__(16) u32 pw[4][2][2048];   // per-wave dbuf stage, 64KB

  const int tid = threadIdx.x;
  const int vb = ((blockIdx.x & 7) << 7) + (blockIdx.x >> 3);
  const int part = vb >> 8;
  const int w = vb & 255;
  const int b = w >> 7;
  const int qbase = (w & 127) << 6;
  const int t_lo = part << 5;
  const u32* __restrict__ hb_ = hib + ((size_t)b << 18);
  const u32* __restrict__ lb_ = lob + ((size_t)b << 18);
  const float* __restrict__ sqb = sq + (b << 13);

  const int lane = tid & 63, wid = tid >> 6;
  const int qoff = (wid & 1) << 5;
  const int moff = (wid >> 1) << 5;
  const int l15 = lane & 15;
  const int h4 = lane >> 4;
  const int sw = l15 & 7;
  const int lofs = lane << 2;

#define STAGE(BUF, TILE)                                                     \
  {                                                                          \
    const u32* sH_ = hb_ + ((size_t)(TILE) << 11) + (moff << 5);             \
    const u32* sL_ = lb_ + ((size_t)(TILE) << 11) + (moff << 5);             \
    u32* bp_ = &pw[wid][(BUF)][0];                                           \
    gload_lds16(sH_ + lofs, bp_ + lofs);                                     \
    gload_lds16(sH_ + 256 + lofs, bp_ + 256 + lofs);                         \
    gload_lds16(sH_ + 512 + lofs, bp_ + 512 + lofs);                         \
    gload_lds16(sH_ + 768 + lofs, bp_ + 768 + lofs);                         \
    gload_lds16(sL_ + lofs, bp_ + 1024 + lofs);                              \
    gload_lds16(sL_ + 256 + lofs, bp_ + 1280 + lofs);                        \
    gload_lds16(sL_ + 512 + lofs, bp_ + 1536 + lofs);                        \
    gload_lds16(sL_ + 768 + lofs, bp_ + 1792 + lofs);                        \
  }

  STAGE(0, t_lo)
  float sqn0 = sqb[(t_lo << 6) + moff + l15];
  float sqn1 = sqb[(t_lo << 6) + moff + 16 + l15];

  bf16x8 ah[2][2], al[2][2];
#pragma unroll
  for (int g = 0; g < 2; ++g)
#pragma unroll
    for (int s = 0; s < 2; ++s) {
      const int row = qbase + qoff + (g << 4) + l15;
      const int off = row * 32 + ((((s << 2) + h4) ^ sw) << 2);
      u32x4 hv = *(const u32x4*)(hb_ + off);
      u32x4 lv = *(const u32x4*)(lb_ + off);
      hv.x ^= 0x80008000u; hv.y ^= 0x80008000u;
      hv.z ^= 0x80008000u; hv.w ^= 0x80008000u;
      lv.x ^= 0x80008000u; lv.y ^= 0x80008000u;
      lv.z ^= 0x80008000u; lv.w ^= 0x80008000u;
      ah[g][s] = __builtin_bit_cast(bf16x8, hv);
      al[g][s] = __builtin_bit_cast(bf16x8, lv);
    }
  asm volatile("s_waitcnt vmcnt(0)" ::: "memory");
  __builtin_amdgcn_sched_barrier(0);

  u32 d[2][4][KC];
#pragma unroll
  for (int g = 0; g < 2; ++g)
#pragma unroll
    for (int i = 0; i < 4; ++i)
#pragma unroll
      for (int k = 0; k < KC; ++k) d[g][i][k] = 0xffffffffu;

  for (int tau = 0; tau < TPB; ++tau) {
    const int cur = tau & 1;
    const float sq0 = sqn0, sq1 = sqn1;
    if (tau + 1 < TPB) {
      STAGE(cur ^ 1, t_lo + tau + 1)
      sqn0 = sqb[((t_lo + tau + 1) << 6) + moff + l15];
      sqn1 = sqb[((t_lo + tau + 1) << 6) + moff + 16 + l15];
      asm volatile("s_waitcnt vmcnt(10)" ::: "memory");
    } else {
      asm volatile("s_waitcnt vmcnt(0)" ::: "memory");
    }
    __builtin_amdgcn_sched_barrier(0);

    const u32* ppc = &pw[wid][cur][0];
#pragma unroll
    for (int f = 0; f < 2; ++f) {
      const float sqm = ((f ? sq1 : sq0) + 2.f) * 0.5f;
      const int rloc = (f << 4) + l15;
      f32x4 acc[2];
      acc[0] = (f32x4){sqm, sqm, sqm, sqm};
      acc[1] = acc[0];
#pragma unroll
      for (int s = 0; s < 2; ++s) {
        const u32* hp = ppc + rloc * 32 + ((((s << 2) + h4) ^ sw) << 2);
        const bf16x8 bh = __builtin_bit_cast(bf16x8, *(const u32x4*)hp);
        const bf16x8 bl = __builtin_bit_cast(bf16x8, *(const u32x4*)(hp + 1024));
        acc[0] = __builtin_amdgcn_mfma_f32_16x16x32_bf16(ah[0][s], bh, acc[0], 0, 0, 0);
        acc[1] = __builtin_amdgcn_mfma_f32_16x16x32_bf16(ah[1][s], bh, acc[1], 0, 0, 0);
        acc[0] = __builtin_amdgcn_mfma_f32_16x16x32_bf16(al[0][s], bh, acc[0], 0, 0, 0);
        acc[1] = __builtin_amdgcn_mfma_f32_16x16x32_bf16(al[1][s], bh, acc[1], 0, 0, 0);
        acc[0] = __builtin_amdgcn_mfma_f32_16x16x32_bf16(ah[0][s], bl, acc[0], 0, 0, 0);
        acc[1] = __builtin_amdgcn_mfma_f32_16x16x32_bf16(ah[1][s], bl, acc[1], 0, 0, 0);
      }
      const u32 lidx = (u32)((tau << 6) + moff + rloc);
#pragma unroll
      for (int g = 0; g < 2; ++g)
#pragma unroll
        for (int i = 0; i < 4; ++i) {
          const u32 keyv = (__float_as_uint(acc[g][i]) & 0xfffff000u) | lidx;
          insmm<KC>(keyv, d[g][i]);
        }
    }
  }
#undef STAGE
  __syncthreads();

  // ---- transposed bank-skewed merge (two 32-row chunks), KM=16 ----
  u32* dmp = &pw[0][0][0];
  u32* m1b = dmp + 8448;
  u32* m2b = dmp + 12144;
  const int stream = ((wid >> 1) << 4) + l15;
  const int rcb = ((wid & 1) << 4) + (h4 << 2);
#pragma unroll
  for (int chunk = 0; chunk < 2; ++chunk) {
#pragma unroll
    for (int i = 0; i < 4; ++i) {
      const int col = stream * 33 + rcb + i;
#pragma unroll
      for (int k = 0; k < KC; ++k) dmp[k * 1056 + col] = d[chunk][i][k];
    }
    __syncthreads();
    {
      const int rowc = tid >> 3, oct = tid & 7;
      u32 m1[14];
#pragma unroll
      for (int k = 0; k < 14; ++k) m1[k] = 0xffffffffu;
#pragma unroll
      for (int s = 0; s < 4; ++s) {
        const int col = (oct * 4 + s) * 33 + rowc;
#pragma unroll
        for (int j = 0; j < KC; ++j) insmm<14>(dmp[j * 1056 + col], m1);
      }
      const int col = oct * 33 + rowc;
#pragma unroll
      for (int k = 0; k < 14; ++k) m1b[k * 264 + col] = m1[k];
    }
    __syncthreads();
    if (tid < 64) {
      const int rowc = tid >> 1, half = tid & 1;
      u32 m2[KM];
#pragma unroll
      for (int k = 0; k < KM; ++k) m2[k] = 0xffffffffu;
#pragma unroll
      for (int o = 0; o < 4; ++o) {
        const int col = (half * 4 + o) * 33 + rowc;
#pragma unroll
        for (int j = 0; j < 14; ++j) insmm<KM>(m1b[j * 264 + col], m2);
      }
      const int col = half * 33 + rowc;
#pragma unroll
      for (int k = 0; k < KM; ++k) m2b[k * 66 + col] = m2[k];
    }
    __syncthreads();
    if (tid < 32) {
      u32 m3[KM];
#pragma unroll
      for (int k = 0; k < KM; ++k) m3[k] = 0xffffffffu;
#pragma unroll
      for (int h = 0; h < 2; ++h) {
        const int col = h * 33 + tid;
#pragma unroll
        for (int k = 0; k < KM; ++k) insmm<KM>(m2b[k * 66 + col], m3);
      }
      const int row = ((tid >> 4) << 5) + (chunk << 4) + (tid & 15);
      const int rg = (b << 13) + qbase + row;
      u16* cw = cand + (size_t)rg * (NPART * KM) + part * KM;
#pragma unroll
      for (int k = 0; k < KM; ++k)
        cw[k] = (u16)((part << 11) + (m3[k] & 0xfffu));
    }
    __syncthreads();
  }
}

// ---------------- kernel 3: rescore from hi|w16 exact reconstruct -----------
__global__ __launch_bounds__(512) void finalize_kernel(
    const u32* __restrict__ hib, const u32* __restrict__ w16b,
    const float* __restrict__ sq, const u16* __restrict__ cand,
    int* __restrict__ out) {
  __shared__ u64 ex[64 * 66];
  __shared__ u64 hf[128 * 19];
  const int tid = threadIdx.x;
  const int rl = tid >> 3, sub = tid & 7;
  const int row = (blockIdx.x << 6) + rl;
  const int b = row >> 13;
  const int n = row & 8191;
  const float sqn = sq[row];
  const float* __restrict__ sqb = sq + (b << 13);
  const u32* __restrict__ hb_ = hib + ((size_t)b << 18);
  const u32* __restrict__ wb_ = w16b + ((size_t)b << 18);
  float vq[CHN];
  {
    const u32* hq = hb_ + ((size_t)n << 5);
    const u32* wq = wb_ + ((size_t)n << 5);
    const int key = n & 7;
#pragma unroll
    for (int q = 0; q < 8; ++q) {
      const int pq = (q ^ key) << 2;
      const u32x4 hw = *(const u32x4*)(hq + pq);
      const u32x4 ww = *(const u32x4*)(wq + pq);
      const u32 hv[4] = {hw.x, hw.y, hw.z, hw.w};
      const u32 wv[4] = {ww.x, ww.y, ww.z, ww.w};
#pragma unroll
      for (int p2 = 0; p2 < 4; ++p2) {
        vq[8 * q + 2 * p2] =
            __uint_as_float((hv[p2] << 16) | (wv[p2] & 0xffffu));
        vq[8 * q + 2 * p2 + 1] =
            __uint_as_float((hv[p2] & 0xffff0000u) | (wv[p2] >> 16));
      }
    }
  }
  const u16* __restrict__ cr = cand + (size_t)row * 64 + sub * 8;
  u64* exw = ex + rl * 66 + sub * 8;
  for (int j = 0; j < 8; ++j) {
    const int ix = cr[j];
    const u32* hp = hb_ + ((size_t)ix << 5);
    const u32* wp = wb_ + ((size_t)ix << 5);
    const int key = ix & 7;
    float dot = 0.f;
#pragma unroll
    for (int q = 0; q < 8; ++q) {
      const int pq = (q ^ key) << 2;
      const u32x4 hw = *(const u32x4*)(hp + pq);
      const u32x4 ww = *(const u32x4*)(wp + pq);
      const u32 hv[4] = {hw.x, hw.y, hw.z, hw.w};
      const u32 wv[4] = {ww.x, ww.y, ww.z, ww.w};
#pragma unroll
      for (int p2 = 0; p2 < 4; ++p2) {
        const float a = __uint_as_float((hv[p2] << 16) | (wv[p2] & 0xffffu));
        const float c = __uint_as_float((hv[p2] & 0xffff0000u) | (wv[p2] >> 16));
        dot = __fadd_rn(dot, __fmul_rn(vq[8 * q + 2 * p2], a));
        dot = __fadd_rn(dot, __fmul_rn(vq[8 * q + 2 * p2 + 1], c));
      }
    }
    const float dist =
        __fadd_rn(__fsub_rn(sqn, __fmul_rn(2.0f, dot)), sqb[ix]);
    exw[j] = ((u64)mono32(dist) << 32) | (u32)ix;
  }
  __syncthreads();
  if (tid < 128) {
    const int r2 = tid >> 1, hv = tid & 1;
    u64 m18[KF];
#pragma unroll
    for (int k = 0; k < KF; ++k) m18[k] = ~0ull;
    const u64* p = ex + r2 * 66 + hv * 32;
    for (int j = 0; j < 32; ++j) ins64<KF>(p[j], m18);
    u64* wr = hf + tid * 19;
#pragma unroll
    for (int k = 0; k < KF; ++k) wr[k] = m18[k];
  }
  __syncthreads();
  if (tid < 64) {
    u64 m18[KF];
#pragma unroll
    for (int k = 0; k < KF; ++k) m18[k] = ~0ull;
    const u64* p0 = hf + (tid << 1) * 19;
    const u64* p1 = hf + ((tid << 1) + 1) * 19;
    for (int j = 0; j < KF; ++j) ins64<KF>(p0[j], m18);
    for (int j = 0; j < KF; ++j) ins64<KF>(p1[j], m18);
    const int row2 = (blockIdx.x << 6) + tid;
    int* o0 = out + (size_t)row2 * KOUT;
    int* o1 = o0 + NB * NPTS * KOUT;
#pragma unroll
    for (int k = 0; k < KOUT; ++k) {
      o0[k] = (int)(m18[2 * k] & 0xffffffffu);
      o1[k] = row2 & 8191;
    }
  }
}

// ---------------- launcher: 3 kernels, ws = 8.06MB ----------------
extern "C" void kernel_launch(void* const* d_in, const int* in_sizes, int n_in,
                              void* d_out, int out_size, void* d_ws, size_t ws_size,
                              hipStream_t stream) {
  const float* x = (const float*)d_in[0];
  u32* hib = (u32*)d_ws;
  u32* lob = hib + (size_t)NB * NPTS * 32;
  u32* w16b = lob + (size_t)NB * NPTS * 32;
  float* sqg = (float*)(w16b + (size_t)NB * NPTS * 32);
  u16* cand = (u16*)(sqg + NB * NPTS);
  int* out = (int*)d_out;
  prep_kernel<<<dim3(128), dim3(128), 0, stream>>>(x, hib, lob, w16b, sqg);
  knn_part_kernel<<<dim3(1024), dim3(256), 0, stream>>>(hib, lob, sqg, cand);
  finalize_kernel<<<dim3(256), dim3(512), 0, stream>>>(hib, w16b, sqg, cand, out);
}